// Round 1
// baseline (355.149 us; speedup 1.0000x reference)
//
#include <hip/hip_runtime.h>
#include <hip/hip_bf16.h>
#include <math.h>

#define BSZ 4096
#define DIM 256
#define EPSV 1e-6f
#define SCALEV 20.0f

typedef short bf16x8 __attribute__((ext_vector_type(8)));
typedef float floatx4 __attribute__((ext_vector_type(4)));

__device__ inline unsigned short f2bf(float f) {
    unsigned u = __float_as_uint(f);
    unsigned r = (u + 0x7FFFu + ((u >> 16) & 1u)) >> 16;
    return (unsigned short)r;
}

// One wave per row: convert fp32 row -> bf16, compute row L2 norm.
__global__ __launch_bounds__(256)
void norm_convert_kernel(const float* __restrict__ src,
                         unsigned short* __restrict__ dst,
                         float* __restrict__ norms) {
    int row  = blockIdx.x * 4 + (threadIdx.x >> 6);
    int lane = threadIdx.x & 63;
    float4 v = ((const float4*)(src + (size_t)row * DIM))[lane];
    float ss = v.x * v.x + v.y * v.y + v.z * v.z + v.w * v.w;
    ushort4 h;
    h.x = f2bf(v.x); h.y = f2bf(v.y); h.z = f2bf(v.z); h.w = f2bf(v.w);
    ((ushort4*)dst)[row * (DIM / 4) + lane] = h;
    #pragma unroll
    for (int m = 32; m; m >>= 1) ss += __shfl_xor(ss, m, 64);
    if (lane == 0) norms[row] = sqrtf(ss);
}

// One wave per row pair: fp32 diagonal score s_ii.
__global__ __launch_bounds__(256)
void diag_kernel(const float* __restrict__ X, const float* __restrict__ Y,
                 const float* __restrict__ nx, const float* __restrict__ ny,
                 float* __restrict__ diag) {
    int row  = blockIdx.x * 4 + (threadIdx.x >> 6);
    int lane = threadIdx.x & 63;
    float4 x = ((const float4*)(X + (size_t)row * DIM))[lane];
    float4 y = ((const float4*)(Y + (size_t)row * DIM))[lane];
    float d = x.x * y.x + x.y * y.y + x.z * y.z + x.w * y.w;
    #pragma unroll
    for (int m = 32; m; m >>= 1) d += __shfl_xor(d, m, 64);
    if (lane == 0)
        diag[row] = d * SCALEV / fmaxf(nx[row] * ny[row], EPSV);
}

// Block computes a 64x64 tile of exp(score-20); accumulates row/col partial
// sums into global rowsum/colsum via atomics.
// 4 waves in 2x2; each wave: 2x2 grid of 16x16x32 bf16 MFMA tiles.
__global__ __launch_bounds__(256)
void pair_scores_kernel(const unsigned short* __restrict__ Xb,
                        const unsigned short* __restrict__ Yb,
                        const float* __restrict__ nx,
                        const float* __restrict__ ny,
                        float* __restrict__ rowsum,
                        float* __restrict__ colsum) {
    __shared__ float tile[64][65];
    int tid  = threadIdx.x;
    int lane = tid & 63;
    int wave = tid >> 6;
    int wm = wave >> 1, wn = wave & 1;
    int q = lane >> 4, l = lane & 15;
    int bi = blockIdx.x * 64, bj = blockIdx.y * 64;

    int r0 = bi + wm * 32;   // wave's first X row
    int c0 = bj + wn * 32;   // wave's first Y row

    const unsigned short* xbase = Xb + (size_t)(r0 + l) * DIM + q * 8;
    const unsigned short* ybase = Yb + (size_t)(c0 + l) * DIM + q * 8;

    floatx4 acc00 = {0.f,0.f,0.f,0.f}, acc01 = {0.f,0.f,0.f,0.f};
    floatx4 acc10 = {0.f,0.f,0.f,0.f}, acc11 = {0.f,0.f,0.f,0.f};

    #pragma unroll
    for (int ks = 0; ks < DIM; ks += 32) {
        bf16x8 a0 = *(const bf16x8*)(xbase + ks);
        bf16x8 a1 = *(const bf16x8*)(xbase + 16 * DIM + ks);
        bf16x8 b0 = *(const bf16x8*)(ybase + ks);
        bf16x8 b1 = *(const bf16x8*)(ybase + 16 * DIM + ks);
        acc00 = __builtin_amdgcn_mfma_f32_16x16x32_bf16(a0, b0, acc00, 0, 0, 0);
        acc01 = __builtin_amdgcn_mfma_f32_16x16x32_bf16(a0, b1, acc01, 0, 0, 0);
        acc10 = __builtin_amdgcn_mfma_f32_16x16x32_bf16(a1, b0, acc10, 0, 0, 0);
        acc11 = __builtin_amdgcn_mfma_f32_16x16x32_bf16(a1, b1, acc11, 0, 0, 0);
    }

    // C/D layout (verified): col = lane&15, row = (lane>>4)*4 + reg
    #pragma unroll
    for (int ai = 0; ai < 2; ai++) {
        #pragma unroll
        for (int bt = 0; bt < 2; bt++) {
            floatx4 a = (ai == 0) ? (bt == 0 ? acc00 : acc01)
                                  : (bt == 0 ? acc10 : acc11);
            int cl = wn * 32 + bt * 16 + l;
            float nyv = ny[bj + cl];
            #pragma unroll
            for (int reg = 0; reg < 4; reg++) {
                int rl = wm * 32 + ai * 16 + q * 4 + reg;
                float nxv = nx[bi + rl];
                float s = a[reg] * SCALEV / fmaxf(nxv * nyv, EPSV);
                tile[rl][cl] = __expf(s - SCALEV);
            }
        }
    }
    __syncthreads();

    if (tid < 64) {
        float s = 0.f;
        #pragma unroll 8
        for (int j = 0; j < 64; j++) s += tile[tid][j];
        atomicAdd(&rowsum[bi + tid], s);
    } else if (tid < 128) {
        int c = tid - 64;
        float s = 0.f;
        #pragma unroll 8
        for (int i = 0; i < 64; i++) s += tile[i][c];
        atomicAdd(&colsum[bj + c], s);
    }
}

// total = sum over 4 pairs, 4096 rows of [20 + 0.5*(log r + log c) - d] / 8192
__global__ __launch_bounds__(256)
void final_reduce_kernel(const float* __restrict__ rowsum,
                         const float* __restrict__ colsum,
                         const float* __restrict__ diag,
                         float* __restrict__ out) {
    __shared__ float red[256];
    float acc = 0.f;
    for (int idx = threadIdx.x; idx < 4 * BSZ; idx += 256) {
        acc += SCALEV + 0.5f * (logf(rowsum[idx]) + logf(colsum[idx])) - diag[idx];
    }
    red[threadIdx.x] = acc;
    __syncthreads();
    for (int s = 128; s; s >>= 1) {
        if (threadIdx.x < s) red[threadIdx.x] += red[threadIdx.x + s];
        __syncthreads();
    }
    if (threadIdx.x == 0) out[0] = red[0] / (BSZ * 2.0f);
}

extern "C" void kernel_launch(void* const* d_in, const int* in_sizes, int n_in,
                              void* d_out, int out_size, void* d_ws, size_t ws_size,
                              hipStream_t stream) {
    const float* in_anchor = (const float*)d_in[0];
    const float* in_pos    = (const float*)d_in[1];
    // d_in[2] (reference_anchor) intentionally unused, matching the reference.
    const float* in_rtext  = (const float*)d_in[3];
    const float* in_rvis   = (const float*)d_in[4];

    char* ws = (char*)d_ws;
    // Layout: bf16 copies (4 slots), then fp32 arrays.
    unsigned short* bf = (unsigned short*)ws;               // 4 * B * D ushort
    size_t bf_bytes = (size_t)4 * BSZ * DIM * sizeof(unsigned short);
    float* norms  = (float*)(ws + bf_bytes);                // 4 * B
    float* rowsum = norms  + 4 * BSZ;                       // 4 * B
    float* colsum = rowsum + 4 * BSZ;                       // 4 * B
    float* diag   = colsum + 4 * BSZ;                       // 4 * B

    // rowsum/colsum must start at zero (ws is poisoned before every launch)
    hipMemsetAsync(rowsum, 0, 2 * 4 * BSZ * sizeof(float), stream);

    const float* srcs[4] = {in_anchor, in_pos, in_rtext, in_rvis};
    for (int m = 0; m < 4; m++) {
        norm_convert_kernel<<<BSZ / 4, 256, 0, stream>>>(
            srcs[m], bf + (size_t)m * BSZ * DIM, norms + m * BSZ);
    }

    static const int pairs[4][2] = {{0, 1}, {0, 2}, {1, 2}, {1, 3}};
    for (int p = 0; p < 4; p++) {
        int x = pairs[p][0], y = pairs[p][1];
        diag_kernel<<<BSZ / 4, 256, 0, stream>>>(
            srcs[x], srcs[y], norms + x * BSZ, norms + y * BSZ, diag + p * BSZ);
        dim3 grid(BSZ / 64, BSZ / 64);
        pair_scores_kernel<<<grid, 256, 0, stream>>>(
            bf + (size_t)x * BSZ * DIM, bf + (size_t)y * BSZ * DIM,
            norms + x * BSZ, norms + y * BSZ,
            rowsum + p * BSZ, colsum + p * BSZ);
    }

    final_reduce_kernel<<<1, 256, 0, stream>>>(rowsum, colsum, diag, (float*)d_out);
}

// Round 2
// 230.604 us; speedup vs baseline: 1.5401x; 1.5401x over previous
//
#include <hip/hip_runtime.h>
#include <hip/hip_bf16.h>
#include <math.h>

#define BSZ 4096
#define DIM 256
#define SCALEV 20.0f

typedef short bf16x8 __attribute__((ext_vector_type(8)));
typedef float floatx4 __attribute__((ext_vector_type(4)));

__device__ inline unsigned short f2bf(float f) {
    unsigned u = __float_as_uint(f);
    unsigned r = (u + 0x7FFFu + ((u >> 16) & 1u)) >> 16;
    return (unsigned short)r;
}

// One wave per row: convert fp32 row -> bf16, compute rn = sqrt(20)/||row||.
// grid = (BSZ/4, 4 matrices)
__global__ __launch_bounds__(256)
void norm_convert_kernel(const float* __restrict__ a0, const float* __restrict__ a1,
                         const float* __restrict__ a2, const float* __restrict__ a3,
                         unsigned short* __restrict__ dst, float* __restrict__ rn) {
    const float* srcs[4] = {a0, a1, a2, a3};
    int m    = blockIdx.y;
    const float* src = srcs[m];
    int row  = blockIdx.x * 4 + (threadIdx.x >> 6);
    int lane = threadIdx.x & 63;
    float4 v = ((const float4*)(src + (size_t)row * DIM))[lane];
    float ss = v.x * v.x + v.y * v.y + v.z * v.z + v.w * v.w;
    ushort4 h;
    h.x = f2bf(v.x); h.y = f2bf(v.y); h.z = f2bf(v.z); h.w = f2bf(v.w);
    ((ushort4*)(dst + (size_t)m * BSZ * DIM))[row * (DIM / 4) + lane] = h;
    #pragma unroll
    for (int s = 32; s; s >>= 1) ss += __shfl_xor(ss, s, 64);
    if (lane == 0)
        rn[m * BSZ + row] = sqrtf(SCALEV) * rsqrtf(fmaxf(ss, 1e-12f));
}

// One wave per (pair,row): fp32 diagonal score s_ii = dot * rx_i * ry_i.
// grid = (BSZ/4, 4 pairs)
__global__ __launch_bounds__(256)
void diag_kernel(const float* __restrict__ a0, const float* __restrict__ a1,
                 const float* __restrict__ a2, const float* __restrict__ a3,
                 const float* __restrict__ rn, float* __restrict__ diag) {
    const int PX[4] = {0, 0, 1, 1};
    const int PY[4] = {1, 2, 2, 3};
    const float* srcs[4] = {a0, a1, a2, a3};
    int p = blockIdx.y;
    const float* X = srcs[PX[p]];
    const float* Y = srcs[PY[p]];
    int row  = blockIdx.x * 4 + (threadIdx.x >> 6);
    int lane = threadIdx.x & 63;
    float4 x = ((const float4*)(X + (size_t)row * DIM))[lane];
    float4 y = ((const float4*)(Y + (size_t)row * DIM))[lane];
    float d = x.x * y.x + x.y * y.y + x.z * y.z + x.w * y.w;
    #pragma unroll
    for (int s = 32; s; s >>= 1) d += __shfl_xor(d, s, 64);
    if (lane == 0)
        diag[p * BSZ + row] = d * rn[PX[p] * BSZ + row] * rn[PY[p] * BSZ + row];
}

// Block computes a 128x128 tile of exp(score-20) for pair blockIdx.z.
// 4 waves in 2x2; each wave a 64x64 sub-tile via 4x4 of 16x16x32 bf16 MFMA.
// Row/col partial sums reduced in-register (shuffles) -> global atomics.
__global__ __launch_bounds__(256)
void pair_scores_kernel(const unsigned short* __restrict__ bf,
                        const float* __restrict__ rn,
                        float* __restrict__ rowsum,
                        float* __restrict__ colsum) {
    const int PX[4] = {0, 0, 1, 1};
    const int PY[4] = {1, 2, 2, 3};
    int p = blockIdx.z;
    const unsigned short* Xb = bf + (size_t)PX[p] * BSZ * DIM;
    const unsigned short* Yb = bf + (size_t)PY[p] * BSZ * DIM;
    const float* rnx = rn + PX[p] * BSZ;
    const float* rny = rn + PY[p] * BSZ;
    float* rs = rowsum + p * BSZ;
    float* cs = colsum + p * BSZ;

    __shared__ float srx[128];
    __shared__ float sry[128];

    int tid  = threadIdx.x;
    int lane = tid & 63;
    int wave = tid >> 6;
    int wm = wave >> 1, wn = wave & 1;
    int q = lane >> 4, l = lane & 15;
    int bi = blockIdx.x * 128, bj = blockIdx.y * 128;

    if (tid < 128) srx[tid] = rnx[bi + tid];
    else           sry[tid - 128] = rny[bj + tid - 128];

    int r0 = bi + wm * 64;
    int c0 = bj + wn * 64;
    const unsigned short* xb = Xb + (size_t)(r0 + l) * DIM + q * 8;
    const unsigned short* yb = Yb + (size_t)(c0 + l) * DIM + q * 8;

    floatx4 acc[4][4] = {};

    #pragma unroll
    for (int ks = 0; ks < DIM; ks += 32) {
        bf16x8 a[4], b[4];
        #pragma unroll
        for (int t = 0; t < 4; t++) {
            a[t] = *(const bf16x8*)(xb + (size_t)t * 16 * DIM + ks);
            b[t] = *(const bf16x8*)(yb + (size_t)t * 16 * DIM + ks);
        }
        #pragma unroll
        for (int i = 0; i < 4; i++)
            #pragma unroll
            for (int j = 0; j < 4; j++)
                acc[i][j] = __builtin_amdgcn_mfma_f32_16x16x32_bf16(a[i], b[j], acc[i][j], 0, 0, 0);
    }

    __syncthreads();  // srx/sry visible

    // C/D layout: col = lane&15 (=l), row = (lane>>4)*4 + reg (=q*4+reg)
    float ry[4];
    #pragma unroll
    for (int bt = 0; bt < 4; bt++) ry[bt] = sry[wn * 64 + bt * 16 + l];

    #pragma unroll
    for (int ai = 0; ai < 4; ai++) {
        float rx[4];
        #pragma unroll
        for (int r = 0; r < 4; r++) rx[r] = srx[wm * 64 + ai * 16 + q * 4 + r];
        #pragma unroll
        for (int bt = 0; bt < 4; bt++) {
            #pragma unroll
            for (int r = 0; r < 4; r++)
                acc[ai][bt][r] = __expf(acc[ai][bt][r] * rx[r] * ry[bt] - SCALEV);
        }
    }

    // Row sums: combine 4 column-tiles in-reg, reduce across the 16 l-lanes.
    #pragma unroll
    for (int ai = 0; ai < 4; ai++) {
        float r4[4];
        #pragma unroll
        for (int r = 0; r < 4; r++)
            r4[r] = acc[ai][0][r] + acc[ai][1][r] + acc[ai][2][r] + acc[ai][3][r];
        #pragma unroll
        for (int r = 0; r < 4; r++) {
            #pragma unroll
            for (int s = 1; s < 16; s <<= 1) r4[r] += __shfl_xor(r4[r], s, 64);
        }
        #pragma unroll
        for (int r = 0; r < 4; r++)
            if (l == r)
                atomicAdd(&rs[bi + wm * 64 + ai * 16 + q * 4 + r], r4[r]);
    }

    // Col sums: combine 4 row-tiles + 4 regs in-reg, reduce across quads.
    #pragma unroll
    for (int bt = 0; bt < 4; bt++) {
        float c1 = 0.f;
        #pragma unroll
        for (int ai = 0; ai < 4; ai++)
            #pragma unroll
            for (int r = 0; r < 4; r++) c1 += acc[ai][bt][r];
        c1 += __shfl_xor(c1, 16, 64);
        c1 += __shfl_xor(c1, 32, 64);
        if (q == 0)
            atomicAdd(&cs[bj + wn * 64 + bt * 16 + l], c1);
    }
}

// total = sum over 4 pairs, 4096 rows of [20 + 0.5*(log r + log c) - d] / 8192
__global__ __launch_bounds__(256)
void final_reduce_kernel(const float* __restrict__ rowsum,
                         const float* __restrict__ colsum,
                         const float* __restrict__ diag,
                         float* __restrict__ out) {
    __shared__ float red[256];
    float acc = 0.f;
    for (int idx = threadIdx.x; idx < 4 * BSZ; idx += 256) {
        acc += SCALEV + 0.5f * (logf(rowsum[idx]) + logf(colsum[idx])) - diag[idx];
    }
    red[threadIdx.x] = acc;
    __syncthreads();
    for (int s = 128; s; s >>= 1) {
        if (threadIdx.x < s) red[threadIdx.x] += red[threadIdx.x + s];
        __syncthreads();
    }
    if (threadIdx.x == 0) out[0] = red[0] / (BSZ * 2.0f);
}

extern "C" void kernel_launch(void* const* d_in, const int* in_sizes, int n_in,
                              void* d_out, int out_size, void* d_ws, size_t ws_size,
                              hipStream_t stream) {
    const float* in_anchor = (const float*)d_in[0];
    const float* in_pos    = (const float*)d_in[1];
    // d_in[2] (reference_anchor) intentionally unused, matching the reference.
    const float* in_rtext  = (const float*)d_in[3];
    const float* in_rvis   = (const float*)d_in[4];

    char* ws = (char*)d_ws;
    unsigned short* bf = (unsigned short*)ws;               // 4 * B * D ushort
    size_t bf_bytes = (size_t)4 * BSZ * DIM * sizeof(unsigned short);
    float* rn     = (float*)(ws + bf_bytes);                // 4 * B
    float* rowsum = rn     + 4 * BSZ;                       // 4 * B
    float* colsum = rowsum + 4 * BSZ;                       // 4 * B
    float* diag   = colsum + 4 * BSZ;                       // 4 * B

    hipMemsetAsync(rowsum, 0, 2 * 4 * BSZ * sizeof(float), stream);

    norm_convert_kernel<<<dim3(BSZ / 4, 4), 256, 0, stream>>>(
        in_anchor, in_pos, in_rtext, in_rvis, bf, rn);

    diag_kernel<<<dim3(BSZ / 4, 4), 256, 0, stream>>>(
        in_anchor, in_pos, in_rtext, in_rvis, rn, diag);

    pair_scores_kernel<<<dim3(BSZ / 128, BSZ / 128, 4), 256, 0, stream>>>(
        bf, rn, rowsum, colsum);

    final_reduce_kernel<<<1, 256, 0, stream>>>(rowsum, colsum, diag, (float*)d_out);
}

// Round 3
// 181.364 us; speedup vs baseline: 1.9582x; 1.2715x over previous
//
#include <hip/hip_runtime.h>
#include <hip/hip_bf16.h>
#include <math.h>

#define BSZ 4096
#define DIM 256
// 20 * log2(e): scores are produced in exp2-domain by pre-scaling rows.
#define SC20L2E 28.853900817779268f

typedef short bf16x8 __attribute__((ext_vector_type(8)));
typedef float floatx4 __attribute__((ext_vector_type(4)));

__device__ __forceinline__ unsigned short f2bf(float f) {
    unsigned u = __float_as_uint(f);
    return (unsigned short)((u + 0x7FFFu + ((u >> 16) & 1u)) >> 16);
}

// Async global->LDS, 16 B per lane. lds dest must be wave-uniform
// (HW scatters to base + lane*16).
__device__ __forceinline__ void async_cp16(void* lds, const void* g) {
    __builtin_amdgcn_global_load_lds(
        (__attribute__((address_space(1))) unsigned int*)(unsigned long long)g,
        (__attribute__((address_space(3))) unsigned int*)lds,
        16, 0, 0);
}

// One wave per row index: load row `r` of all 4 matrices once.
// Produces: bf16 rows pre-scaled by sqrt(20*log2e)/||row||  (so MFMA outputs
// score*log2e directly), fp32 diagonal scores for the 4 pairs, and zeroes
// rowsum/colsum (first 64 blocks).
__global__ __launch_bounds__(256)
void prep_kernel(const float* __restrict__ a0, const float* __restrict__ a1,
                 const float* __restrict__ a2, const float* __restrict__ a3,
                 unsigned short* __restrict__ bfo, float* __restrict__ diag,
                 float* __restrict__ rowsum, float* __restrict__ colsum) {
    const float* srcs[4] = {a0, a1, a2, a3};
    int w = threadIdx.x >> 6, lane = threadIdx.x & 63;
    int row = blockIdx.x * 4 + w;

    float4 v[4];
    float red[8];
    #pragma unroll
    for (int m = 0; m < 4; m++) {
        v[m] = ((const float4*)(srcs[m] + (size_t)row * DIM))[lane];
        red[m] = v[m].x * v[m].x + v[m].y * v[m].y + v[m].z * v[m].z + v[m].w * v[m].w;
    }
    // pair dots: (0,1) (0,2) (1,2) (1,3)
    red[4] = v[0].x * v[1].x + v[0].y * v[1].y + v[0].z * v[1].z + v[0].w * v[1].w;
    red[5] = v[0].x * v[2].x + v[0].y * v[2].y + v[0].z * v[2].z + v[0].w * v[2].w;
    red[6] = v[1].x * v[2].x + v[1].y * v[2].y + v[1].z * v[2].z + v[1].w * v[2].w;
    red[7] = v[1].x * v[3].x + v[1].y * v[3].y + v[1].z * v[3].z + v[1].w * v[3].w;

    #pragma unroll
    for (int i = 0; i < 8; i++) {
        #pragma unroll
        for (int s = 32; s; s >>= 1) red[i] += __shfl_xor(red[i], s, 64);
    }

    float rinv[4];
    #pragma unroll
    for (int m = 0; m < 4; m++) rinv[m] = rsqrtf(fmaxf(red[m], 1e-24f));

    const float sq = sqrtf(SC20L2E);
    #pragma unroll
    for (int m = 0; m < 4; m++) {
        float sc = sq * rinv[m];
        ushort4 h;
        h.x = f2bf(v[m].x * sc); h.y = f2bf(v[m].y * sc);
        h.z = f2bf(v[m].z * sc); h.w = f2bf(v[m].w * sc);
        ((ushort4*)(bfo + (size_t)m * BSZ * DIM))[row * (DIM / 4) + lane] = h;
    }

    if (lane == 0) {
        diag[0 * BSZ + row] = red[4] * 20.0f * rinv[0] * rinv[1];
        diag[1 * BSZ + row] = red[5] * 20.0f * rinv[0] * rinv[2];
        diag[2 * BSZ + row] = red[6] * 20.0f * rinv[1] * rinv[2];
        diag[3 * BSZ + row] = red[7] * 20.0f * rinv[1] * rinv[3];
    }
    if (blockIdx.x < 64) {
        int idx = blockIdx.x * 256 + threadIdx.x;
        rowsum[idx] = 0.f;
        colsum[idx] = 0.f;
    }
}

// 128x128 tile of exp2(u - 28.854) (u = score*log2e from pre-scaled bf16),
// m97-style: double-buffered LDS panels staged with global_load_lds width=16,
// fragments via ds_read_b128. 4 waves in 2x2, each 64x64 via 4x4 MFMA tiles.
// LDS chunk layout [quarter][row] (16B chunks) -> 2-way-only bank aliasing.
__global__ __launch_bounds__(256)
void pair_scores_kernel(const unsigned short* __restrict__ bf,
                        float* __restrict__ rowsum,
                        float* __restrict__ colsum) {
    const int PX[4] = {0, 0, 1, 1};
    const int PY[4] = {1, 2, 2, 3};
    int p = blockIdx.z;
    const unsigned short* Xb = bf + (size_t)PX[p] * BSZ * DIM;
    const unsigned short* Yb = bf + (size_t)PY[p] * BSZ * DIM;
    float* rs = rowsum + p * BSZ;
    float* cs = colsum + p * BSZ;

    __shared__ __align__(16) unsigned char smem[2][16384];

    int tid  = threadIdx.x;
    int lane = tid & 63;
    int w    = tid >> 6;
    int wm = w >> 1, wn = w & 1;
    int q = lane >> 4, l = lane & 15;
    int bi = blockIdx.x * 128, bj = blockIdx.y * 128;

    // Staging: thread t loads chunks t and t+256 of both panels.
    // chunk c -> quarter = c>>7 (k-offset quarter*8), row = c&127.
    int c1 = tid + 256;
    int qa0 = tid >> 7, ra0 = tid & 127;
    int qa1 = c1 >> 7,  ra1 = c1 & 127;
    const unsigned short* gA0 = Xb + (size_t)(bi + ra0) * DIM + qa0 * 8;
    const unsigned short* gA1 = Xb + (size_t)(bi + ra1) * DIM + qa1 * 8;
    const unsigned short* gB0 = Yb + (size_t)(bj + ra0) * DIM + qa0 * 8;
    const unsigned short* gB1 = Yb + (size_t)(bj + ra1) * DIM + qa1 * 8;

    // Fragment read offsets (bytes): chunk = q*128 + row_local.
    unsigned aoff = (unsigned)(q * 128 + wm * 64 + l) * 16u;
    unsigned boff = 8192u + (unsigned)(q * 128 + wn * 64 + l) * 16u;

    floatx4 acc[4][4] = {};

    // stage k-step 0 into buf 0
    {
        unsigned char* sb = smem[0];
        async_cp16(sb + w * 1024,         gA0);
        async_cp16(sb + 4096 + w * 1024,  gA1);
        async_cp16(sb + 8192 + w * 1024,  gB0);
        async_cp16(sb + 12288 + w * 1024, gB1);
    }

    #pragma unroll
    for (int ks = 0; ks < 8; ks++) {
        __syncthreads();   // staging of buf[ks&1] complete (vmcnt drained)
        if (ks < 7) {
            int ko = (ks + 1) * 32;
            unsigned char* sn = smem[(ks + 1) & 1];
            async_cp16(sn + w * 1024,         gA0 + ko);
            async_cp16(sn + 4096 + w * 1024,  gA1 + ko);
            async_cp16(sn + 8192 + w * 1024,  gB0 + ko);
            async_cp16(sn + 12288 + w * 1024, gB1 + ko);
        }
        unsigned char* sb = smem[ks & 1];
        bf16x8 a[4], b[4];
        #pragma unroll
        for (int t = 0; t < 4; t++) {
            a[t] = *(const bf16x8*)(sb + aoff + t * 256);
            b[t] = *(const bf16x8*)(sb + boff + t * 256);
        }
        #pragma unroll
        for (int i = 0; i < 4; i++)
            #pragma unroll
            for (int j = 0; j < 4; j++)
                acc[i][j] = __builtin_amdgcn_mfma_f32_16x16x32_bf16(a[i], b[j], acc[i][j], 0, 0, 0);
    }

    // Epilogue: exp2, then in-register row/col sums -> global atomics.
    // C/D layout: col = l, row = q*4 + reg (within each 16x16 tile).
    #pragma unroll
    for (int ai = 0; ai < 4; ai++)
        #pragma unroll
        for (int bt = 0; bt < 4; bt++)
            #pragma unroll
            for (int r = 0; r < 4; r++)
                acc[ai][bt][r] = exp2f(acc[ai][bt][r] - SC20L2E);

    #pragma unroll
    for (int ai = 0; ai < 4; ai++) {
        float r4[4];
        #pragma unroll
        for (int r = 0; r < 4; r++)
            r4[r] = acc[ai][0][r] + acc[ai][1][r] + acc[ai][2][r] + acc[ai][3][r];
        #pragma unroll
        for (int r = 0; r < 4; r++) {
            #pragma unroll
            for (int s = 1; s < 16; s <<= 1) r4[r] += __shfl_xor(r4[r], s, 64);
        }
        #pragma unroll
        for (int r = 0; r < 4; r++)
            if (l == r)
                atomicAdd(&rs[bi + wm * 64 + ai * 16 + q * 4 + r], r4[r]);
    }

    #pragma unroll
    for (int bt = 0; bt < 4; bt++) {
        float c1s = 0.f;
        #pragma unroll
        for (int ai = 0; ai < 4; ai++)
            #pragma unroll
            for (int r = 0; r < 4; r++) c1s += acc[ai][bt][r];
        c1s += __shfl_xor(c1s, 16, 64);
        c1s += __shfl_xor(c1s, 32, 64);
        if (q == 0)
            atomicAdd(&cs[bj + wn * 64 + bt * 16 + l], c1s);
    }
}

// total = sum over 4 pairs, 4096 rows of [20 + 0.5*(log r + log c) - d] / 8192
__global__ __launch_bounds__(1024)
void final_reduce_kernel(const float* __restrict__ rowsum,
                         const float* __restrict__ colsum,
                         const float* __restrict__ diag,
                         float* __restrict__ out) {
    __shared__ float red[1024];
    int tid = threadIdx.x;
    float acc = 0.f;
    for (int idx = tid; idx < 4 * BSZ; idx += 1024)
        acc += 0.5f * (__logf(rowsum[idx]) + __logf(colsum[idx])) - diag[idx];
    red[tid] = acc;
    __syncthreads();
    for (int s = 512; s; s >>= 1) {
        if (tid < s) red[tid] += red[tid + s];
        __syncthreads();
    }
    if (tid == 0)
        out[0] = (red[0] + 20.0f * 4 * BSZ) / (BSZ * 2.0f);
}

extern "C" void kernel_launch(void* const* d_in, const int* in_sizes, int n_in,
                              void* d_out, int out_size, void* d_ws, size_t ws_size,
                              hipStream_t stream) {
    const float* in_anchor = (const float*)d_in[0];
    const float* in_pos    = (const float*)d_in[1];
    // d_in[2] (reference_anchor) intentionally unused, matching the reference.
    const float* in_rtext  = (const float*)d_in[3];
    const float* in_rvis   = (const float*)d_in[4];

    char* ws = (char*)d_ws;
    unsigned short* bf = (unsigned short*)ws;               // 4 * B * D ushort
    size_t bf_bytes = (size_t)4 * BSZ * DIM * sizeof(unsigned short);
    float* rowsum = (float*)(ws + bf_bytes);                // 4 * B
    float* colsum = rowsum + 4 * BSZ;                       // 4 * B
    float* diag   = colsum + 4 * BSZ;                       // 4 * B

    prep_kernel<<<BSZ / 4, 256, 0, stream>>>(
        in_anchor, in_pos, in_rtext, in_rvis, bf, diag, rowsum, colsum);

    pair_scores_kernel<<<dim3(BSZ / 128, BSZ / 128, 4), 256, 0, stream>>>(
        bf, rowsum, colsum);

    final_reduce_kernel<<<1, 1024, 0, stream>>>(rowsum, colsum, diag, (float*)d_out);
}

// Round 4
// 121.510 us; speedup vs baseline: 2.9228x; 1.4926x over previous
//
#include <hip/hip_runtime.h>
#include <math.h>

#define BSZ 4096
#define DIM 256
// 20 * log2(e): rows are pre-scaled by sqrt(20*log2e)/||row|| so the MFMA
// emits u = score*log2e; exp2(u - SC20L2E) == exp(score - 20) exactly.
#define SC20L2E 28.853900817779268f

typedef float floatx4 __attribute__((ext_vector_type(4)));

__device__ __forceinline__ void async_cp16(void* lds, const void* g) {
    __builtin_amdgcn_global_load_lds(
        (__attribute__((address_space(1))) unsigned int*)(unsigned long long)g,
        (__attribute__((address_space(3))) unsigned int*)lds,
        16, 0, 0);
}

// One wave per row index: load row r of all 4 matrices once.
// Outputs: fp8 e4m3 rows pre-scaled by sqrt(20*log2e)/||row||, fp32 diagonal
// scores for the 4 pairs, and zeroes rowsum/colsum (first 64 blocks).
__global__ __launch_bounds__(256)
void prep_kernel(const float* __restrict__ a0, const float* __restrict__ a1,
                 const float* __restrict__ a2, const float* __restrict__ a3,
                 unsigned char* __restrict__ f8, float* __restrict__ diag,
                 float* __restrict__ rowsum, float* __restrict__ colsum) {
    const float* srcs[4] = {a0, a1, a2, a3};
    int w = threadIdx.x >> 6, lane = threadIdx.x & 63;
    int row = blockIdx.x * 4 + w;

    float4 v[4];
    float red[8];
    #pragma unroll
    for (int m = 0; m < 4; m++) {
        v[m] = ((const float4*)(srcs[m] + (size_t)row * DIM))[lane];
        red[m] = v[m].x * v[m].x + v[m].y * v[m].y + v[m].z * v[m].z + v[m].w * v[m].w;
    }
    // pair dots: (0,1) (0,2) (1,2) (1,3)
    red[4] = v[0].x * v[1].x + v[0].y * v[1].y + v[0].z * v[1].z + v[0].w * v[1].w;
    red[5] = v[0].x * v[2].x + v[0].y * v[2].y + v[0].z * v[2].z + v[0].w * v[2].w;
    red[6] = v[1].x * v[2].x + v[1].y * v[2].y + v[1].z * v[2].z + v[1].w * v[2].w;
    red[7] = v[1].x * v[3].x + v[1].y * v[3].y + v[1].z * v[3].z + v[1].w * v[3].w;

    #pragma unroll
    for (int i = 0; i < 8; i++) {
        #pragma unroll
        for (int s = 32; s; s >>= 1) red[i] += __shfl_xor(red[i], s, 64);
    }

    float rinv[4];
    #pragma unroll
    for (int m = 0; m < 4; m++) rinv[m] = rsqrtf(fmaxf(red[m], 1e-24f));

    const float sq = sqrtf(SC20L2E);
    #pragma unroll
    for (int m = 0; m < 4; m++) {
        float sc = sq * rinv[m];
        int pk = __builtin_amdgcn_cvt_pk_fp8_f32(v[m].x * sc, v[m].y * sc, 0, false);
        pk = __builtin_amdgcn_cvt_pk_fp8_f32(v[m].z * sc, v[m].w * sc, pk, true);
        ((unsigned int*)(f8 + (size_t)m * BSZ * DIM))[row * 64 + lane] = (unsigned int)pk;
    }

    if (lane == 0) {
        diag[0 * BSZ + row] = red[4] * 20.0f * rinv[0] * rinv[1];
        diag[1 * BSZ + row] = red[5] * 20.0f * rinv[0] * rinv[2];
        diag[2 * BSZ + row] = red[6] * 20.0f * rinv[1] * rinv[2];
        diag[3 * BSZ + row] = red[7] * 20.0f * rinv[1] * rinv[3];
    }
    if (blockIdx.x < 64) {
        int idx = blockIdx.x * 256 + threadIdx.x;
        rowsum[idx] = 0.f;
        colsum[idx] = 0.f;
    }
}

// 128x128 tile of exp(score-20) for pair blockIdx.z, fp8 e4m3 MFMA.
// FULL-K LDS staging (A 32KB + B 32KB = 64KB -> 2 blocks/CU): one barrier per
// block, then 8 barrier-free k-steps of ds_read_b64 + mfma_16x16x32_fp8.
// LDS swizzle: slot(row,kq) = row*16 + ((kq+row)&15)  (16-B chunks) -- applied
// on the GLOBAL address side so global_load_lds's lane*16 scatter still works;
// makes fragment reads ~2-way bank aliased (free).
__global__ __launch_bounds__(256)
void pair_scores_kernel(const unsigned char* __restrict__ f8,
                        float* __restrict__ rowsum,
                        float* __restrict__ colsum) {
    const int PX[4] = {0, 0, 1, 1};
    const int PY[4] = {1, 2, 2, 3};
    int p = blockIdx.z;
    const unsigned char* Xb = f8 + (size_t)PX[p] * BSZ * DIM;
    const unsigned char* Yb = f8 + (size_t)PY[p] * BSZ * DIM;
    float* rs = rowsum + p * BSZ;
    float* cs = colsum + p * BSZ;

    __shared__ __align__(16) unsigned char smem[65536];

    int tid  = threadIdx.x;
    int lane = tid & 63;
    int w    = tid >> 6;
    int wm = w >> 1, wn = w & 1;
    int q = lane >> 4, l = lane & 15;
    int bi = blockIdx.x * 128, bj = blockIdx.y * 128;

    // ---- stage both full-K panels (2048 16-B slots each) ----
    #pragma unroll
    for (int i = 0; i < 8; i++) {
        int sb  = i * 256 + w * 64;
        int s   = sb + lane;
        int row = s >> 4;
        int kq  = ((s & 15) - row) & 15;
        async_cp16(smem + sb * 16,         Xb + (size_t)(bi + row) * 256 + kq * 16);
        async_cp16(smem + 32768 + sb * 16, Yb + (size_t)(bj + row) * 256 + kq * 16);
    }
    __syncthreads();  // single drain for the whole block

    int qh = q >> 1, qb = (q & 1) * 8;
    int ra[4], rb[4];
    #pragma unroll
    for (int t = 0; t < 4; t++) {
        ra[t] = wm * 64 + t * 16 + l;
        rb[t] = wn * 64 + t * 16 + l;
    }

    floatx4 acc[4][4] = {};
    #pragma unroll
    for (int ks = 0; ks < 8; ks++) {
        int k2 = ks * 2 + qh;
        long long a[4], b[4];
        #pragma unroll
        for (int t = 0; t < 4; t++) {
            a[t] = *(const long long*)(smem + ra[t] * 256 + (((k2 + ra[t]) & 15) << 4) + qb);
            b[t] = *(const long long*)(smem + 32768 + rb[t] * 256 + (((k2 + rb[t]) & 15) << 4) + qb);
        }
        #pragma unroll
        for (int i = 0; i < 4; i++)
            #pragma unroll
            for (int j = 0; j < 4; j++)
                acc[i][j] = __builtin_amdgcn_mfma_f32_16x16x32_fp8_fp8(a[i], b[j], acc[i][j], 0, 0, 0);
    }

    // ---- epilogue: exp2, value-splitting butterfly reductions, atomics ----
    // C/D layout per 16x16 tile: col = l, row = q*4 + reg.
    #pragma unroll
    for (int ai = 0; ai < 4; ai++)
        #pragma unroll
        for (int bt = 0; bt < 4; bt++)
            #pragma unroll
            for (int r = 0; r < 4; r++)
                acc[ai][bt][r] = exp2f(acc[ai][bt][r] - SC20L2E);

    // Row sums: v[t], t = ai*4+r, reduce over the 16 l-lanes; result t -> lane l==t.
    float v[16];
    #pragma unroll
    for (int ai = 0; ai < 4; ai++)
        #pragma unroll
        for (int r = 0; r < 4; r++)
            v[ai * 4 + r] = acc[ai][0][r] + acc[ai][1][r] + acc[ai][2][r] + acc[ai][3][r];

    float w1[8];
    #pragma unroll
    for (int k = 0; k < 8; k++) {
        float snd = (l & 1) ? v[2 * k] : v[2 * k + 1];
        float got = __shfl_xor(snd, 1, 64);
        w1[k] = ((l & 1) ? v[2 * k + 1] : v[2 * k]) + got;
    }
    float w2[4];
    #pragma unroll
    for (int m = 0; m < 4; m++) {
        float snd = ((l >> 1) & 1) ? w1[2 * m] : w1[2 * m + 1];
        float got = __shfl_xor(snd, 2, 64);
        w2[m] = (((l >> 1) & 1) ? w1[2 * m + 1] : w1[2 * m]) + got;
    }
    float w3[2];
    #pragma unroll
    for (int n = 0; n < 2; n++) {
        float snd = ((l >> 2) & 1) ? w2[2 * n] : w2[2 * n + 1];
        float got = __shfl_xor(snd, 4, 64);
        w3[n] = (((l >> 2) & 1) ? w2[2 * n + 1] : w2[2 * n]) + got;
    }
    {
        float snd = ((l >> 3) & 1) ? w3[0] : w3[1];
        float got = __shfl_xor(snd, 8, 64);
        float wr = (((l >> 3) & 1) ? w3[1] : w3[0]) + got;
        // lane l holds rowsum for t=l: ai=l>>2, r=l&3
        atomicAdd(&rs[bi + wm * 64 + ((l >> 2) << 4) + q * 4 + (l & 3)], wr);
    }

    // Col sums: c4[bt], reduce over the 4 q-groups; result bt -> q==bt.
    float c4[4];
    #pragma unroll
    for (int bt = 0; bt < 4; bt++) {
        float s = 0.f;
        #pragma unroll
        for (int ai = 0; ai < 4; ai++)
            #pragma unroll
            for (int r = 0; r < 4; r++) s += acc[ai][bt][r];
        c4[bt] = s;
    }
    float e0, e1, fsum;
    {
        float snd = (q & 1) ? c4[0] : c4[1];
        float got = __shfl_xor(snd, 16, 64);
        e0 = ((q & 1) ? c4[1] : c4[0]) + got;
    }
    {
        float snd = (q & 1) ? c4[2] : c4[3];
        float got = __shfl_xor(snd, 16, 64);
        e1 = ((q & 1) ? c4[3] : c4[2]) + got;
    }
    {
        float snd = ((q >> 1) & 1) ? e0 : e1;
        float got = __shfl_xor(snd, 32, 64);
        fsum = (((q >> 1) & 1) ? e1 : e0) + got;
    }
    atomicAdd(&cs[bj + wn * 64 + (q << 4) + l], fsum);
}

// total = [ sum over 4 pairs, 4096 rows of 0.5*(ln r + ln c) - d  + 20*4B ] / 2B
__global__ __launch_bounds__(1024)
void final_reduce_kernel(const float* __restrict__ rowsum,
                         const float* __restrict__ colsum,
                         const float* __restrict__ diag,
                         float* __restrict__ out) {
    __shared__ float red[1024];
    int tid = threadIdx.x;
    float acc = 0.f;
    #pragma unroll 4
    for (int idx = tid; idx < 4 * BSZ; idx += 1024)
        acc += 0.5f * (__logf(rowsum[idx]) + __logf(colsum[idx])) - diag[idx];
    red[tid] = acc;
    __syncthreads();
    for (int s = 512; s; s >>= 1) {
        if (tid < s) red[tid] += red[tid + s];
        __syncthreads();
    }
    if (tid == 0)
        out[0] = (red[0] + 20.0f * 4 * BSZ) / (BSZ * 2.0f);
}

extern "C" void kernel_launch(void* const* d_in, const int* in_sizes, int n_in,
                              void* d_out, int out_size, void* d_ws, size_t ws_size,
                              hipStream_t stream) {
    const float* in_anchor = (const float*)d_in[0];
    const float* in_pos    = (const float*)d_in[1];
    // d_in[2] (reference_anchor) intentionally unused, matching the reference.
    const float* in_rtext  = (const float*)d_in[3];
    const float* in_rvis   = (const float*)d_in[4];

    char* ws = (char*)d_ws;
    unsigned char* f8 = (unsigned char*)ws;                 // 4 * B * D fp8
    size_t f8_bytes = (size_t)4 * BSZ * DIM;
    float* rowsum = (float*)(ws + f8_bytes);                // 4 * B
    float* colsum = rowsum + 4 * BSZ;                       // 4 * B
    float* diag   = colsum + 4 * BSZ;                       // 4 * B

    prep_kernel<<<BSZ / 4, 256, 0, stream>>>(
        in_anchor, in_pos, in_rtext, in_rvis, f8, diag, rowsum, colsum);

    pair_scores_kernel<<<dim3(BSZ / 128, BSZ / 128, 4), 256, 0, stream>>>(
        f8, rowsum, colsum);

    final_reduce_kernel<<<1, 1024, 0, stream>>>(rowsum, colsum, diag, (float*)d_out);
}